// Round 18
// baseline (79.927 us; speedup 1.0000x reference)
//
#include <hip/hip_runtime.h>
#include <hip/hip_bf16.h>
#include <math.h>

#define B_   8
#define N_   1024
#define FIN  128
#define FOUT 128
#define H_   8
#define NEG  0.2f
#define LOG2E 1.4426950408889634f

typedef __attribute__((ext_vector_type(4))) float f32x4;
typedef __attribute__((ext_vector_type(8))) short s16x8;

static __device__ __forceinline__ unsigned short f2bf(float f) {
    unsigned int u = __float_as_uint(f);
    unsigned int r = (u + 0x7fffu + ((u >> 16) & 1u)) >> 16;   // RNE (software)
    return (unsigned short)r;
}

static __device__ __forceinline__ unsigned short f2bf_hw(float f) {
    union { __hip_bfloat16 b; unsigned short u; } cv;
    cv.b = __float2bfloat16(f);
    return cv.u;
}

// ---------------- K_PREP: fused {bias | WT | hbT | s1/s2 | zero-out} -----------------
// grid 1736: [0,1024) bias, [1024,1032) WT, [1032,1160) hbT,
//            [1160,1224) s1/s2 per (b,h), [1224,1736) zero-out
__global__ __launch_bounds__(256) void k_prep(const int* __restrict__ adj,
                                              const float* __restrict__ bias,
                                              const float* __restrict__ W,
                                              const float* __restrict__ a,
                                              const float* __restrict__ hsrc,
                                              float* __restrict__ biasm,
                                              unsigned short* __restrict__ WT,
                                              float* __restrict__ s1,
                                              float* __restrict__ s2T,
                                              unsigned short* __restrict__ hbT,
                                              float* __restrict__ outz) {
    __shared__ float tf[64][132];
    __shared__ float wal[2][128];
    const int blk = blockIdx.x;
    const int t   = threadIdx.x;

    if (blk < 1024) {
        // ---- biasm[i][j] = adj ? bias*log2e : -inf (f32), 4 elems/thread
        const int base = (blk * 256 + t) * 4;
        int4   av = *(const int4*)&adj[base];
        float4 bv = *(const float4*)&bias[base];
        const float NINF = -__builtin_inff();
        float4 r;
        r.x = av.x ? bv.x * LOG2E : NINF;
        r.y = av.y ? bv.y * LOG2E : NINF;
        r.z = av.z ? bv.z * LOG2E : NINF;
        r.w = av.w ? bv.w * LOG2E : NINF;
        *(float4*)&biasm[base] = r;
    } else if (blk < 1032) {
        // ---- WT[h][fout][fin] bf16
        const int hd  = blk - 1024;
        const int fo  = t >> 1;
        const int fi0 = (t & 1) * 64;
        const float* src = W + (size_t)hd * FIN * FOUT;
        unsigned short* dst = WT + ((size_t)hd * FOUT + fo) * FIN + fi0;
#pragma unroll
        for (int c = 0; c < 8; ++c) {
            s16x8 v;
#pragma unroll
            for (int u = 0; u < 8; ++u)
                v[u] = (short)f2bf(src[(size_t)(fi0 + c * 8 + u) * FOUT + fo]);
            *(s16x8*)(dst + c * 8) = v;
        }
    } else if (blk < 1160) {
        // ---- hbT[b][k][n] bf16 transpose
        const int bn0 = (blk - 1032) * 64;
        const int b   = bn0 >> 10;
        const int n0  = bn0 & 1023;
        {
            const int r = t >> 2, k0 = (t & 3) * 32;
            const float* src = hsrc + (size_t)(bn0 + r) * FIN + k0;
#pragma unroll
            for (int c = 0; c < 8; ++c)
                *(float4*)&tf[r][k0 + c * 4] = *(const float4*)&src[c * 4];
        }
        __syncthreads();
        {
            const int k   = t >> 1;
            const int seg = (t & 1) * 32;
            unsigned short* dst = hbT + ((size_t)b * FIN + k) * N_ + n0 + seg;
#pragma unroll
            for (int c = 0; c < 4; ++c) {
                s16x8 v;
#pragma unroll
                for (int u = 0; u < 8; ++u)
                    v[u] = (short)f2bf_hw(tf[seg + c * 8 + u][k]);
                *(s16x8*)(dst + c * 8) = v;
            }
        }
    } else if (blk < 1224) {
        // ---- s1/s2 for (b,hd): compute wa slice in LDS, then 8-lane-group row dots
        const int q  = blk - 1160;
        const int b  = q >> 3, hd = q & 7;
        {
            const int which = t >> 7, k = t & 127;
            const float* wrow = W + ((size_t)hd * FIN + k) * FOUT;
            const float* av   = a + (size_t)hd * 2 * FOUT + which * FOUT;
            float s = 0.f;
#pragma unroll 8
            for (int f = 0; f < FOUT; f += 4) {
                float4 wv = *(const float4*)&wrow[f];
                float4 a4 = *(const float4*)&av[f];
                s += wv.x * a4.x + wv.y * a4.y + wv.z * a4.z + wv.w * a4.w;
            }
            wal[which][k] = s * LOG2E;
        }
        __syncthreads();
        const int rg = t >> 3;            // 0..31
        const int f0 = (t & 7) * 16;
        for (int c = 0; c < 32; ++c) {
            const int n = c * 32 + rg;
            const float* hr = hsrc + ((size_t)(b << 10) + n) * FIN + f0;
            float s1p = 0.f, s2p = 0.f;
#pragma unroll
            for (int u = 0; u < 4; ++u) {
                float4 hv = *(const float4*)&hr[u * 4];
                float4 w1 = *(const float4*)&wal[0][f0 + u * 4];
                float4 w2 = *(const float4*)&wal[1][f0 + u * 4];
                s1p += hv.x * w1.x + hv.y * w1.y + hv.z * w1.z + hv.w * w1.w;
                s2p += hv.x * w2.x + hv.y * w2.y + hv.z * w2.z + hv.w * w2.w;
            }
            s1p += __shfl_xor(s1p, 1); s1p += __shfl_xor(s1p, 2); s1p += __shfl_xor(s1p, 4);
            s2p += __shfl_xor(s2p, 1); s2p += __shfl_xor(s2p, 2); s2p += __shfl_xor(s2p, 4);
            if ((t & 7) == 0) {
                s1[((size_t)(b << 10) + n) * 8 + hd] = s1p;
                s2T[(size_t)hd * (B_ * N_) + (b << 10) + n] = s2p;
            }
        }
    } else {
        // ---- zero out[]
        const int base = ((blk - 1224) * 256 + t) * 8;
        const float4 z4 = make_float4(0.f, 0.f, 0.f, 0.f);
        *(float4*)&outz[base]     = z4;
        *(float4*)&outz[base + 4] = z4;
    }
}

// ---------------- K2: 4-heads-per-block fused P-gen + MFMA (P.h) + G@W epilogue ------
// grid 512: XCD k <- batch k; per batch: 2 head-groups x 32 i-tiles.
// B-tile staged ONCE per 4 heads; each Bl ds_read feeds 4 MFMAs.
__global__ __launch_bounds__(256, 2) void k_pv2(const unsigned short* __restrict__ hbT,
                                                const float* __restrict__ s1,
                                                const float* __restrict__ s2T,
                                                const float* __restrict__ biasm,
                                                const unsigned short* __restrict__ WT,
                                                float* __restrict__ out) {
    __shared__ __align__(16) unsigned short Pm[4 * 2048];    // 16 KB, XOR-swizzled
    __shared__ __align__(16) unsigned short Bl[128 * 64];    // 16 KB, XOR-swizzled
    __shared__ __align__(16) unsigned short Gl[32][136];     // 8.5 KB, padded
    __shared__ float Zl[4][32];
    const int t    = threadIdx.x;
    const int lane = t & 63;
    const int wave = t >> 6;
    const int wg  = blockIdx.x;
    const int swz = ((wg & 7) << 6) | (wg >> 3);   // bijective (512 % 8 == 0)
    const int i0  = (swz & 31) * 32;
    const int hg  = (swz >> 5) & 1;
    const int b   = swz >> 6;
    const int hd0 = hg * 4;

    const int prow = t >> 3;          // 0..31
    const int pj0  = (t & 7) * 8;     // 0..56
    const int pchk = (t & 7) ^ (prow & 7);   // swizzled P chunk for store
    const int gi   = (b << 10) + i0 + prow;
    float s1v[4];
#pragma unroll
    for (int h = 0; h < 4; ++h) s1v[h] = s1[(size_t)gi * 8 + hd0 + h];
    const float* bm_row = biasm + (size_t)(i0 + prow) * N_;
    const float* s2p[4];
#pragma unroll
    for (int h = 0; h < 4; ++h)
        s2p[h] = s2T + (size_t)(hd0 + h) * (B_ * N_) + (b << 10);

    const unsigned short* hpS = hbT + (size_t)b * FIN * N_;
    const int brow = t >> 3;
    const int bc   = t & 7;

    const int wr = (wave & 1) * 16;
    const int wc = (wave >> 1) * 64;
    const int arow = wr + (lane & 15);
    const int koff = (lane >> 4) * 8;

    f32x4 acc[4][4];
#pragma unroll
    for (int h = 0; h < 4; ++h)
#pragma unroll
        for (int j = 0; j < 4; ++j) acc[h][j] = (f32x4){0.f, 0.f, 0.f, 0.f};
    float zh[4] = {0.f, 0.f, 0.f, 0.f};

    float4 bmv[2], sv[4][2];
    s16x8 Breg[4];

    auto load_it = [&](int j0) {
#pragma unroll
        for (int q = 0; q < 2; ++q)
            bmv[q] = *(const float4*)&bm_row[j0 + pj0 + q * 4];
#pragma unroll
        for (int h = 0; h < 4; ++h)
#pragma unroll
            for (int q = 0; q < 2; ++q)
                sv[h][q] = *(const float4*)&s2p[h][j0 + pj0 + q * 4];
    };
    auto bload = [&](int j0) {
#pragma unroll
        for (int q = 0; q < 4; ++q)
            Breg[q] = *(const s16x8*)&hpS[(size_t)(brow + q * 32) * N_ + j0 + bc * 8];
    };
    auto phaseA = [&]() {
#pragma unroll
        for (int q = 0; q < 4; ++q) {
            int row = brow + q * 32;
            *(s16x8*)&Bl[row * 64 + ((bc ^ (row & 7)) * 8)] = Breg[q];
        }
#pragma unroll
        for (int h = 0; h < 4; ++h) {
            s16x8 pv;
#pragma unroll
            for (int q = 0; q < 2; ++q) {
                float x0 = s1v[h] + sv[h][q].x; x0 = fmaxf(x0, NEG * x0) + bmv[q].x;
                float x1 = s1v[h] + sv[h][q].y; x1 = fmaxf(x1, NEG * x1) + bmv[q].y;
                float x2 = s1v[h] + sv[h][q].z; x2 = fmaxf(x2, NEG * x2) + bmv[q].z;
                float x3 = s1v[h] + sv[h][q].w; x3 = fmaxf(x3, NEG * x3) + bmv[q].w;
                float p0 = exp2f(x0);   // exp2(-inf) = 0 handles the adj mask
                float p1 = exp2f(x1);
                float p2 = exp2f(x2);
                float p3 = exp2f(x3);
                zh[h] += (p0 + p1) + (p2 + p3);
                pv[q * 4 + 0] = (short)f2bf_hw(p0);
                pv[q * 4 + 1] = (short)f2bf_hw(p1);
                pv[q * 4 + 2] = (short)f2bf_hw(p2);
                pv[q * 4 + 3] = (short)f2bf_hw(p3);
            }
            *(s16x8*)&Pm[h * 2048 + prow * 64 + pchk * 8] = pv;
        }
    };

    // ---- main loop: G_tile(h) = P(h) . h — one staged B serves 4 heads
    bload(0);
    load_it(0);
    for (int it = 0; it < 16; ++it) {
        const int j0 = it * 64;
        phaseA();
        __syncthreads();
        if (it < 15) { bload(j0 + 64); load_it(j0 + 64); }
#pragma unroll
        for (int kw = 0; kw < 2; ++kw) {
            const int chunk = kw * 4 + (lane >> 4);
            const int aoff = arow * 64 + ((chunk ^ (arow & 7)) * 8);
            s16x8 a0 = *(const s16x8*)&Pm[aoff];
            s16x8 a1 = *(const s16x8*)&Pm[2048 + aoff];
            s16x8 a2 = *(const s16x8*)&Pm[4096 + aoff];
            s16x8 a3 = *(const s16x8*)&Pm[6144 + aoff];
#pragma unroll
            for (int fc = 0; fc < 4; ++fc) {
                const int r = wc + fc * 16 + (lane & 15);
                s16x8 bf = *(const s16x8*)&Bl[r * 64 + ((chunk ^ (r & 7)) * 8)];
                acc[0][fc] = __builtin_amdgcn_mfma_f32_16x16x32_bf16(a0, bf, acc[0][fc], 0, 0, 0);
                acc[1][fc] = __builtin_amdgcn_mfma_f32_16x16x32_bf16(a1, bf, acc[1][fc], 0, 0, 0);
                acc[2][fc] = __builtin_amdgcn_mfma_f32_16x16x32_bf16(a2, bf, acc[2][fc], 0, 0, 0);
                acc[3][fc] = __builtin_amdgcn_mfma_f32_16x16x32_bf16(a3, bf, acc[3][fc], 0, 0, 0);
            }
        }
        __syncthreads();
    }

    // ---- Z for 4 heads (8 lanes per row)
#pragma unroll
    for (int h = 0; h < 4; ++h) {
        float z = zh[h];
        z += __shfl_xor(z, 1); z += __shfl_xor(z, 2); z += __shfl_xor(z, 4);
        if ((t & 7) == 0) Zl[h][prow] = 0.125f / z;   // folds softmax norm + head-mean
    }

    // ---- epilogue: out += sum_h G(h) @ W[hd0+h]; W half1 staged into dead P region
    unsigned short* Pf = &Pm[0];    // 16 KB >= 128x64 shorts
    const int wr2 = wr, wc2 = wc;
    f32x4 acc2[4];
#pragma unroll
    for (int j = 0; j < 4; ++j) acc2[j] = (f32x4){0.f, 0.f, 0.f, 0.f};

    s16x8 WregA[4], WregB[4];
    {
        const unsigned short* Ws = WT + (size_t)hd0 * FOUT * FIN;
#pragma unroll
        for (int q = 0; q < 4; ++q) {
            WregA[q] = *(const s16x8*)&Ws[(size_t)(brow + q * 32) * FIN + bc * 8];
            WregB[q] = *(const s16x8*)&Ws[(size_t)(brow + q * 32) * FIN + 64 + bc * 8];
        }
    }
    __syncthreads();   // Zl visible; Pm/Bl free (all waves past last MFMA)

#pragma unroll
    for (int h = 0; h < 4; ++h) {
        // write scaled G(h) into Gl
#pragma unroll
        for (int r = 0; r < 4; ++r) {
            const int il = wr + (lane >> 4) * 4 + r;
            const float sc = Zl[h][il];
#pragma unroll
            for (int fc = 0; fc < 4; ++fc)
                Gl[il][wc + fc * 16 + (lane & 15)] = f2bf_hw(acc[h][fc][r] * sc);
        }
        // stage both W halves (half0 -> Bl, half1 -> Pf)
#pragma unroll
        for (int q = 0; q < 4; ++q) {
            int row = brow + q * 32;
            *(s16x8*)&Bl[row * 64 + ((bc ^ (row & 7)) * 8)] = WregA[q];
            *(s16x8*)&Pf[row * 64 + ((bc ^ (row & 7)) * 8)] = WregB[q];
        }
        // prefetch next head's W
        if (h < 3) {
            const unsigned short* Ws = WT + (size_t)(hd0 + h + 1) * FOUT * FIN;
#pragma unroll
            for (int q = 0; q < 4; ++q) {
                WregA[q] = *(const s16x8*)&Ws[(size_t)(brow + q * 32) * FIN + bc * 8];
                WregB[q] = *(const s16x8*)&Ws[(size_t)(brow + q * 32) * FIN + 64 + bc * 8];
            }
        }
        __syncthreads();   // Gl(h) + W halves visible
#pragma unroll
        for (int kw = 0; kw < 2; ++kw) {     // k 0..63 from Bl
            const int chunk = kw * 4 + (lane >> 4);
            s16x8 a0 = *(const s16x8*)&Gl[wr2 + (lane & 15)][kw * 32 + koff];
#pragma unroll
            for (int fc = 0; fc < 4; ++fc) {
                const int rb = wc2 + fc * 16 + (lane & 15);
                s16x8 bf = *(const s16x8*)&Bl[rb * 64 + ((chunk ^ (rb & 7)) * 8)];
                acc2[fc] = __builtin_amdgcn_mfma_f32_16x16x32_bf16(a0, bf, acc2[fc], 0, 0, 0);
            }
        }
#pragma unroll
        for (int kw = 0; kw < 2; ++kw) {     // k 64..127 from Pf
            const int chunk = kw * 4 + (lane >> 4);
            s16x8 a0 = *(const s16x8*)&Gl[wr2 + (lane & 15)][64 + kw * 32 + koff];
#pragma unroll
            for (int fc = 0; fc < 4; ++fc) {
                const int rb = wc2 + fc * 16 + (lane & 15);
                s16x8 bf = *(const s16x8*)&Pf[rb * 64 + ((chunk ^ (rb & 7)) * 8)];
                acc2[fc] = __builtin_amdgcn_mfma_f32_16x16x32_bf16(a0, bf, acc2[fc], 0, 0, 0);
            }
        }
        __syncthreads();   // all waves done reading Gl/Bl/Pf before next head's writes
    }

    // ---- accumulate 4-head partial into out (2 head-groups race via atomics)
#pragma unroll
    for (int r = 0; r < 4; ++r) {
        const int il = wr2 + (lane >> 4) * 4 + r;
        float* op = out + ((size_t)((b << 10) + i0 + il)) * FOUT + wc2 + (lane & 15);
#pragma unroll
        for (int fc = 0; fc < 4; ++fc)
            unsafeAtomicAdd(op + fc * 16, acc2[fc][r]);
    }
}

extern "C" void kernel_launch(void* const* d_in, const int* in_sizes, int n_in,
                              void* d_out, int out_size, void* d_ws, size_t ws_size,
                              hipStream_t stream) {
    const float* hsrc = (const float*)d_in[0];
    const int*   adj  = (const int*)d_in[1];
    const float* bias = (const float*)d_in[2];
    const float* W    = (const float*)d_in[3];
    const float* a    = (const float*)d_in[4];
    float* out = (float*)d_out;

    char* ws = (char*)d_ws;
    unsigned short* hbT = (unsigned short*)ws;                 // 2 MB (bf16 h^T per batch)
    float* s1    = (float*)(ws + 2097152);                     // 256 KB
    float* s2T   = s1 + 65536;                                 // 256 KB
    float* biasm = s2T + 65536;                                // 4 MB (f32, log2e-scaled)
    unsigned short* WT = (unsigned short*)(biasm + N_ * N_);   // 256 KB

    k_prep<<<dim3(1736), 256, 0, stream>>>(adj, bias, W, a, hsrc,
                                           biasm, WT, s1, s2T, hbT, out);
    k_pv2<<<dim3(512), 256, 0, stream>>>(hbT, s1, s2T, biasm, WT, out);
}

// Round 19
// 72.418 us; speedup vs baseline: 1.1037x; 1.1037x over previous
//
#include <hip/hip_runtime.h>
#include <hip/hip_bf16.h>
#include <math.h>

#define B_   8
#define N_   1024
#define FIN  128
#define FOUT 128
#define H_   8
#define NEG  0.2f
#define LOG2E 1.4426950408889634f

typedef __attribute__((ext_vector_type(4))) float f32x4;
typedef __attribute__((ext_vector_type(8))) short s16x8;

static __device__ __forceinline__ unsigned short f2bf(float f) {
    unsigned int u = __float_as_uint(f);
    unsigned int r = (u + 0x7fffu + ((u >> 16) & 1u)) >> 16;   // RNE (software)
    return (unsigned short)r;
}

static __device__ __forceinline__ unsigned short f2bf_hw(float f) {
    union { __hip_bfloat16 b; unsigned short u; } cv;
    cv.b = __float2bfloat16(f);
    return cv.u;
}

// ---------------- K_PREP: fused {bias | WT | hbT | s1/s2-fine | zero-out} ------------
// grid 2184: [0,1024) bias, [1024,1032) WT, [1032,1160) hbT,
//            [1160,1672) s1/s2 per (b,h,eighth), [1672,2184) zero-out
__global__ __launch_bounds__(256) void k_prep(const int* __restrict__ adj,
                                              const float* __restrict__ bias,
                                              const float* __restrict__ W,
                                              const float* __restrict__ a,
                                              const float* __restrict__ hsrc,
                                              float* __restrict__ biasm,
                                              unsigned short* __restrict__ WT,
                                              float* __restrict__ s1,
                                              float* __restrict__ s2T,
                                              unsigned short* __restrict__ hbT,
                                              float* __restrict__ outz) {
    __shared__ float tf[64][132];
    __shared__ float wal[2][128];
    const int blk = blockIdx.x;
    const int t   = threadIdx.x;

    if (blk < 1024) {
        // ---- biasm[i][j] = adj ? bias*log2e : -inf (f32), 4 elems/thread
        const int base = (blk * 256 + t) * 4;
        int4   av = *(const int4*)&adj[base];
        float4 bv = *(const float4*)&bias[base];
        const float NINF = -__builtin_inff();
        float4 r;
        r.x = av.x ? bv.x * LOG2E : NINF;
        r.y = av.y ? bv.y * LOG2E : NINF;
        r.z = av.z ? bv.z * LOG2E : NINF;
        r.w = av.w ? bv.w * LOG2E : NINF;
        *(float4*)&biasm[base] = r;
    } else if (blk < 1032) {
        // ---- WT[h][fout][fin] bf16
        const int hd  = blk - 1024;
        const int fo  = t >> 1;
        const int fi0 = (t & 1) * 64;
        const float* src = W + (size_t)hd * FIN * FOUT;
        unsigned short* dst = WT + ((size_t)hd * FOUT + fo) * FIN + fi0;
#pragma unroll
        for (int c = 0; c < 8; ++c) {
            s16x8 v;
#pragma unroll
            for (int u = 0; u < 8; ++u)
                v[u] = (short)f2bf(src[(size_t)(fi0 + c * 8 + u) * FOUT + fo]);
            *(s16x8*)(dst + c * 8) = v;
        }
    } else if (blk < 1160) {
        // ---- hbT[b][k][n] bf16 transpose
        const int bn0 = (blk - 1032) * 64;
        const int b   = bn0 >> 10;
        const int n0  = bn0 & 1023;
        {
            const int r = t >> 2, k0 = (t & 3) * 32;
            const float* src = hsrc + (size_t)(bn0 + r) * FIN + k0;
#pragma unroll
            for (int c = 0; c < 8; ++c)
                *(float4*)&tf[r][k0 + c * 4] = *(const float4*)&src[c * 4];
        }
        __syncthreads();
        {
            const int k   = t >> 1;
            const int seg = (t & 1) * 32;
            unsigned short* dst = hbT + ((size_t)b * FIN + k) * N_ + n0 + seg;
#pragma unroll
            for (int c = 0; c < 4; ++c) {
                s16x8 v;
#pragma unroll
                for (int u = 0; u < 8; ++u)
                    v[u] = (short)f2bf_hw(tf[seg + c * 8 + u][k]);
                *(s16x8*)(dst + c * 8) = v;
            }
        }
    } else if (blk < 1672) {
        // ---- s1/s2 for (b, hd, eighth): wa slice in LDS, then 8-lane-group row dots
        const int q  = blk - 1160;              // 0..511
        const int b  = q >> 6;                  // 0..7
        const int hd = (q >> 3) & 7;            // 0..7
        const int e  = q & 7;                   // 0..7 (row eighth)
        {
            const int which = t >> 7, k = t & 127;
            const float* wrow = W + ((size_t)hd * FIN + k) * FOUT;
            const float* av   = a + (size_t)hd * 2 * FOUT + which * FOUT;
            float s = 0.f;
#pragma unroll 8
            for (int f = 0; f < FOUT; f += 4) {
                float4 wv = *(const float4*)&wrow[f];
                float4 a4 = *(const float4*)&av[f];
                s += wv.x * a4.x + wv.y * a4.y + wv.z * a4.z + wv.w * a4.w;
            }
            wal[which][k] = s * LOG2E;
        }
        __syncthreads();
        const int rg = t >> 3;            // 0..31
        const int f0 = (t & 7) * 16;
#pragma unroll
        for (int c = 0; c < 4; ++c) {
            const int n = e * 128 + c * 32 + rg;
            const float* hr = hsrc + ((size_t)(b << 10) + n) * FIN + f0;
            float s1p = 0.f, s2p = 0.f;
#pragma unroll
            for (int u = 0; u < 4; ++u) {
                float4 hv = *(const float4*)&hr[u * 4];
                float4 w1 = *(const float4*)&wal[0][f0 + u * 4];
                float4 w2 = *(const float4*)&wal[1][f0 + u * 4];
                s1p += hv.x * w1.x + hv.y * w1.y + hv.z * w1.z + hv.w * w1.w;
                s2p += hv.x * w2.x + hv.y * w2.y + hv.z * w2.z + hv.w * w2.w;
            }
            s1p += __shfl_xor(s1p, 1); s1p += __shfl_xor(s1p, 2); s1p += __shfl_xor(s1p, 4);
            s2p += __shfl_xor(s2p, 1); s2p += __shfl_xor(s2p, 2); s2p += __shfl_xor(s2p, 4);
            if ((t & 7) == 0) {
                s1[((size_t)(b << 10) + n) * 8 + hd] = s1p;
                s2T[(size_t)hd * (B_ * N_) + (b << 10) + n] = s2p;
            }
        }
    } else {
        // ---- zero out[]
        const int base = ((blk - 1672) * 256 + t) * 8;
        const float4 z4 = make_float4(0.f, 0.f, 0.f, 0.f);
        *(float4*)&outz[base]     = z4;
        *(float4*)&outz[base + 4] = z4;
    }
}

// ---------------- K2: 2-heads-per-block fused P-gen + MFMA (P.h) + G@W epilogue ------
// (R17 verbatim — measured 49 us)
__global__ __launch_bounds__(256, 4) void k_pv2(const unsigned short* __restrict__ hbT,
                                                const float* __restrict__ s1,
                                                const float* __restrict__ s2T,
                                                const float* __restrict__ biasm,
                                                const unsigned short* __restrict__ WT,
                                                float* __restrict__ out) {
    __shared__ __align__(16) unsigned short P[2][32 * 64];   // 8 KB, XOR-swizzled
    __shared__ __align__(16) unsigned short Bl[128 * 64];    // 16 KB, XOR-swizzled
    __shared__ __align__(16) unsigned short Gl[32][136];     // 8.5 KB, padded
    __shared__ float Zl[2][32];
    const int t    = threadIdx.x;
    const int lane = t & 63;
    const int wave = t >> 6;
    const int wg  = blockIdx.x;
    const int swz = ((wg & 7) << 7) | (wg >> 3);   // bijective (1024 % 8 == 0)
    const int i0  = (swz & 31) * 32;
    const int hp  = (swz >> 5) & 3;
    const int b   = swz >> 7;
    const int hd0 = hp * 2, hd1 = hd0 + 1;

    const int prow = t >> 3;          // 0..31
    const int pj0  = (t & 7) * 8;     // 0..56
    const int pchk = (t & 7) ^ (prow & 7);   // swizzled P chunk for store
    const int gi   = (b << 10) + i0 + prow;
    const float s1v0 = s1[(size_t)gi * 8 + hd0];
    const float s1v1 = s1[(size_t)gi * 8 + hd1];
    const float* bm_row = biasm + (size_t)(i0 + prow) * N_;
    const float* s2p0   = s2T + (size_t)hd0 * (B_ * N_) + (b << 10);
    const float* s2p1   = s2T + (size_t)hd1 * (B_ * N_) + (b << 10);

    const unsigned short* hpS = hbT + (size_t)b * FIN * N_;
    const int brow = t >> 3;
    const int bc   = t & 7;

    const int wr = (wave & 1) * 16;
    const int wc = (wave >> 1) * 64;
    const int arow = wr + (lane & 15);
    const int koff = (lane >> 4) * 8;

    f32x4 acc0[4], acc1[4];
#pragma unroll
    for (int j = 0; j < 4; ++j) {
        acc0[j] = (f32x4){0.f, 0.f, 0.f, 0.f};
        acc1[j] = (f32x4){0.f, 0.f, 0.f, 0.f};
    }
    float z0 = 0.f, z1 = 0.f;

    float4 bmv[2], sv0[2], sv1[2];
    s16x8 Breg[4];

    auto load_it = [&](int j0) {
#pragma unroll
        for (int q = 0; q < 2; ++q) {
            bmv[q] = *(const float4*)&bm_row[j0 + pj0 + q * 4];
            sv0[q] = *(const float4*)&s2p0[j0 + pj0 + q * 4];
            sv1[q] = *(const float4*)&s2p1[j0 + pj0 + q * 4];
        }
    };
    auto bload = [&](int j0) {
#pragma unroll
        for (int q = 0; q < 4; ++q)
            Breg[q] = *(const s16x8*)&hpS[(size_t)(brow + q * 32) * N_ + j0 + bc * 8];
    };
    auto pgen = [&](int h, float s1v, const float4* svh, float& zr) {
        s16x8 pv;
#pragma unroll
        for (int q = 0; q < 2; ++q) {
            float x0 = s1v + svh[q].x; x0 = fmaxf(x0, NEG * x0) + bmv[q].x;
            float x1 = s1v + svh[q].y; x1 = fmaxf(x1, NEG * x1) + bmv[q].y;
            float x2 = s1v + svh[q].z; x2 = fmaxf(x2, NEG * x2) + bmv[q].z;
            float x3 = s1v + svh[q].w; x3 = fmaxf(x3, NEG * x3) + bmv[q].w;
            float p0 = exp2f(x0);   // exp2(-inf) = 0 handles the adj mask
            float p1 = exp2f(x1);
            float p2 = exp2f(x2);
            float p3 = exp2f(x3);
            zr += (p0 + p1) + (p2 + p3);
            pv[q * 4 + 0] = (short)f2bf_hw(p0);
            pv[q * 4 + 1] = (short)f2bf_hw(p1);
            pv[q * 4 + 2] = (short)f2bf_hw(p2);
            pv[q * 4 + 3] = (short)f2bf_hw(p3);
        }
        *(s16x8*)&P[h][prow * 64 + pchk * 8] = pv;
    };
    auto phaseA = [&]() {
#pragma unroll
        for (int q = 0; q < 4; ++q) {
            int row = brow + q * 32;
            *(s16x8*)&Bl[row * 64 + ((bc ^ (row & 7)) * 8)] = Breg[q];
        }
        pgen(0, s1v0, sv0, z0);
        pgen(1, s1v1, sv1, z1);
    };

    // ---- main loop: G_tile(h) = P(h) . h  — one staged B serves both heads
    bload(0);
    load_it(0);
    for (int it = 0; it < 16; ++it) {
        const int j0 = it * 64;
        phaseA();
        __syncthreads();
        if (it < 15) { bload(j0 + 64); load_it(j0 + 64); }
#pragma unroll
        for (int kw = 0; kw < 2; ++kw) {
            const int chunk = kw * 4 + (lane >> 4);
            const int aoff = (chunk ^ (arow & 7)) * 8;
            s16x8 a00 = *(const s16x8*)&P[0][arow * 64 + aoff];
            s16x8 a01 = *(const s16x8*)&P[1][arow * 64 + aoff];
#pragma unroll
            for (int fc = 0; fc < 4; ++fc) {
                const int r = wc + fc * 16 + (lane & 15);
                s16x8 bf = *(const s16x8*)&Bl[r * 64 + ((chunk ^ (r & 7)) * 8)];
                acc0[fc] = __builtin_amdgcn_mfma_f32_16x16x32_bf16(a00, bf, acc0[fc], 0, 0, 0);
                acc1[fc] = __builtin_amdgcn_mfma_f32_16x16x32_bf16(a01, bf, acc1[fc], 0, 0, 0);
            }
        }
        __syncthreads();
    }

    // ---- Z for both heads (8 lanes per row)
    {
        float za = z0, zb = z1;
        za += __shfl_xor(za, 1); za += __shfl_xor(za, 2); za += __shfl_xor(za, 4);
        zb += __shfl_xor(zb, 1); zb += __shfl_xor(zb, 2); zb += __shfl_xor(zb, 4);
        if ((t & 7) == 0) {
            Zl[0][prow] = 0.125f / za;   // folds softmax norm + head-mean
            Zl[1][prow] = 0.125f / zb;
        }
    }

    const unsigned short* Wsrc0 = WT + (size_t)hd0 * FOUT * FIN;
    const unsigned short* Wsrc1 = WT + (size_t)hd1 * FOUT * FIN;
    s16x8 Wreg[4];
#pragma unroll
    for (int q = 0; q < 4; ++q)
        Wreg[q] = *(const s16x8*)&Wsrc0[(size_t)(brow + q * 32) * FIN + bc * 8];
    __syncthreads();   // Zl visible; P/Bl free

    const int wr2 = (wave & 1) * 16;
    const int wc2 = (wave >> 1) * 64;
    f32x4 acc2[4];
#pragma unroll
    for (int j = 0; j < 4; ++j) acc2[j] = (f32x4){0.f, 0.f, 0.f, 0.f};

    auto wstage = [&]() {
#pragma unroll
        for (int q = 0; q < 4; ++q) {
            int row = brow + q * 32;
            *(s16x8*)&Bl[row * 64 + ((bc ^ (row & 7)) * 8)] = Wreg[q];
        }
    };
    auto gw_mfma = [&](int half) {
#pragma unroll
        for (int kw = 0; kw < 2; ++kw) {
            const int chunk = kw * 4 + (lane >> 4);
            s16x8 a0 = *(const s16x8*)&Gl[wr2 + (lane & 15)][half * 64 + kw * 32 + koff];
#pragma unroll
            for (int fc = 0; fc < 4; ++fc) {
                const int rb = wc2 + fc * 16 + (lane & 15);
                s16x8 bf = *(const s16x8*)&Bl[rb * 64 + ((chunk ^ (rb & 7)) * 8)];
                acc2[fc] = __builtin_amdgcn_mfma_f32_16x16x32_bf16(a0, bf, acc2[fc], 0, 0, 0);
            }
        }
    };

    // ---- head 0: out += G0 @ W[hd0]
#pragma unroll
    for (int r = 0; r < 4; ++r) {
        const int il = wr + (lane >> 4) * 4 + r;
        const float sc = Zl[0][il];
#pragma unroll
        for (int fc = 0; fc < 4; ++fc)
            Gl[il][wc + fc * 16 + (lane & 15)] = f2bf_hw(acc0[fc][r] * sc);
    }
    wstage();
#pragma unroll
    for (int q = 0; q < 4; ++q)
        Wreg[q] = *(const s16x8*)&Wsrc0[(size_t)(brow + q * 32) * FIN + 64 + bc * 8];
    __syncthreads();   // Gl(h0) + W0-half0 visible
    gw_mfma(0);
    __syncthreads();
    wstage();
#pragma unroll
    for (int q = 0; q < 4; ++q)
        Wreg[q] = *(const s16x8*)&Wsrc1[(size_t)(brow + q * 32) * FIN + bc * 8];
    __syncthreads();   // W0-half1 visible
    gw_mfma(1);
    __syncthreads();   // all waves done reading Gl(h0) + Bl

    // ---- head 1: out += G1 @ W[hd1]
#pragma unroll
    for (int r = 0; r < 4; ++r) {
        const int il = wr + (lane >> 4) * 4 + r;
        const float sc = Zl[1][il];
#pragma unroll
        for (int fc = 0; fc < 4; ++fc)
            Gl[il][wc + fc * 16 + (lane & 15)] = f2bf_hw(acc1[fc][r] * sc);
    }
    wstage();
#pragma unroll
    for (int q = 0; q < 4; ++q)
        Wreg[q] = *(const s16x8*)&Wsrc1[(size_t)(brow + q * 32) * FIN + 64 + bc * 8];
    __syncthreads();   // Gl(h1) + W1-half0 visible
    gw_mfma(0);
    __syncthreads();
    wstage();
    __syncthreads();   // W1-half1 visible
    gw_mfma(1);

    // ---- accumulate 2-head partial into out
#pragma unroll
    for (int r = 0; r < 4; ++r) {
        const int il = wr2 + (lane >> 4) * 4 + r;
        float* op = out + ((size_t)((b << 10) + i0 + il)) * FOUT + wc2 + (lane & 15);
#pragma unroll
        for (int fc = 0; fc < 4; ++fc)
            unsafeAtomicAdd(op + fc * 16, acc2[fc][r]);
    }
}

extern "C" void kernel_launch(void* const* d_in, const int* in_sizes, int n_in,
                              void* d_out, int out_size, void* d_ws, size_t ws_size,
                              hipStream_t stream) {
    const float* hsrc = (const float*)d_in[0];
    const int*   adj  = (const int*)d_in[1];
    const float* bias = (const float*)d_in[2];
    const float* W    = (const float*)d_in[3];
    const float* a    = (const float*)d_in[4];
    float* out = (float*)d_out;

    char* ws = (char*)d_ws;
    unsigned short* hbT = (unsigned short*)ws;                 // 2 MB (bf16 h^T per batch)
    float* s1    = (float*)(ws + 2097152);                     // 256 KB
    float* s2T   = s1 + 65536;                                 // 256 KB
    float* biasm = s2T + 65536;                                // 4 MB (f32, log2e-scaled)
    unsigned short* WT = (unsigned short*)(biasm + N_ * N_);   // 256 KB

    k_prep<<<dim3(2184), 256, 0, stream>>>(adj, bias, W, a, hsrc,
                                           biasm, WT, s1, s2T, hbT, out);
    k_pv2<<<dim3(1024), 256, 0, stream>>>(hbT, s1, s2T, biasm, WT, out);
}

// Round 20
// 64.022 us; speedup vs baseline: 1.2484x; 1.1311x over previous
//
#include <hip/hip_runtime.h>
#include <hip/hip_bf16.h>
#include <math.h>

#define B_   8
#define N_   1024
#define FIN  128
#define FOUT 128
#define H_   8
#define NEG  0.2f
#define LOG2E 1.4426950408889634f

typedef __attribute__((ext_vector_type(4))) float f32x4;
typedef __attribute__((ext_vector_type(8))) short s16x8;

static __device__ __forceinline__ unsigned short f2bf(float f) {
    unsigned int u = __float_as_uint(f);
    unsigned int r = (u + 0x7fffu + ((u >> 16) & 1u)) >> 16;   // RNE (software)
    return (unsigned short)r;
}

static __device__ __forceinline__ unsigned short f2bf_hw(float f) {
    union { __hip_bfloat16 b; unsigned short u; } cv;
    cv.b = __float2bfloat16(f);
    return cv.u;
}

// ---------------- K_PREP: fused {bias-mask | W->WT | wa | h->hbT} --------------------
// grid 1168 (R17 layout — measured-good balance; wa precomputed ONCE, 8 blocks)
__global__ __launch_bounds__(256) void k_prep(const int* __restrict__ adj,
                                              const float* __restrict__ bias,
                                              const float* __restrict__ W,
                                              const float* __restrict__ a,
                                              const float* __restrict__ hsrc,
                                              float* __restrict__ biasm,
                                              unsigned short* __restrict__ WT,
                                              float* __restrict__ wa,
                                              unsigned short* __restrict__ hbT) {
    __shared__ float tf[64][132];
    const int blk = blockIdx.x;
    const int t   = threadIdx.x;

    if (blk < 1024) {
        // ---- biasm[i][j] = adj ? bias*log2e : -inf (f32), 4 elems/thread
        const int base = (blk * 256 + t) * 4;
        int4   av = *(const int4*)&adj[base];
        float4 bv = *(const float4*)&bias[base];
        const float NINF = -__builtin_inff();
        float4 r;
        r.x = av.x ? bv.x * LOG2E : NINF;
        r.y = av.y ? bv.y * LOG2E : NINF;
        r.z = av.z ? bv.z * LOG2E : NINF;
        r.w = av.w ? bv.w * LOG2E : NINF;
        *(float4*)&biasm[base] = r;
    } else if (blk < 1032) {
        // ---- WT[h][fout][fin] bf16
        const int hd  = blk - 1024;
        const int fo  = t >> 1;
        const int fi0 = (t & 1) * 64;
        const float* src = W + (size_t)hd * FIN * FOUT;
        unsigned short* dst = WT + ((size_t)hd * FOUT + fo) * FIN + fi0;
#pragma unroll
        for (int c = 0; c < 8; ++c) {
            s16x8 v;
#pragma unroll
            for (int u = 0; u < 8; ++u)
                v[u] = (short)f2bf(src[(size_t)(fi0 + c * 8 + u) * FOUT + fo]);
            *(s16x8*)(dst + c * 8) = v;
        }
    } else if (blk < 1040) {
        // ---- wa[h][which][k] = log2e * W[h][k][:] . a[h][which][:]
        const int hd = blk - 1032;
        const int which = t >> 7, k = t & 127;
        const float* wrow = W + ((size_t)hd * FIN + k) * FOUT;
        const float* av   = a + (size_t)hd * 2 * FOUT + which * FOUT;
        float s = 0.f;
#pragma unroll 8
        for (int f = 0; f < FOUT; f += 4) {
            float4 wv = *(const float4*)&wrow[f];
            float4 a4 = *(const float4*)&av[f];
            s += wv.x * a4.x + wv.y * a4.y + wv.z * a4.z + wv.w * a4.w;
        }
        wa[((size_t)hd * 2 + which) * FIN + k] = s * LOG2E;
    } else {
        // ---- hbT[b][k][n] bf16 transpose
        const int bn0 = (blk - 1040) * 64;
        const int b   = bn0 >> 10;
        const int n0  = bn0 & 1023;
        {
            const int r = t >> 2, k0 = (t & 3) * 32;
            const float* src = hsrc + (size_t)(bn0 + r) * FIN + k0;
#pragma unroll
            for (int c = 0; c < 8; ++c)
                *(float4*)&tf[r][k0 + c * 4] = *(const float4*)&src[c * 4];
        }
        __syncthreads();
        {
            const int k   = t >> 1;
            const int seg = (t & 1) * 32;
            unsigned short* dst = hbT + ((size_t)b * FIN + k) * N_ + n0 + seg;
#pragma unroll
            for (int c = 0; c < 4; ++c) {
                s16x8 v;
#pragma unroll
                for (int u = 0; u < 8; ++u)
                    v[u] = (short)f2bf_hw(tf[seg + c * 8 + u][k]);
                *(s16x8*)(dst + c * 8) = v;
            }
        }
    }
}

// ---------------- K0d: s1/s2 (blocks <512, reads precomputed wa) + zero-out ----------
__global__ __launch_bounds__(256) void k_s12(const float* __restrict__ hsrc,
                                             const float* __restrict__ wa,
                                             float* __restrict__ s1,
                                             float* __restrict__ s2T,
                                             float* __restrict__ outz) {
    __shared__ float hrow[16][132];
    __shared__ float wal[16][132];
    const int t   = threadIdx.x;
    const int blk = blockIdx.x;
    if (blk >= 512) {
        const int base = ((blk - 512) * 256 + t) * 8;
        const float4 z4 = make_float4(0.f, 0.f, 0.f, 0.f);
        *(float4*)&outz[base]     = z4;
        *(float4*)&outz[base + 4] = z4;
        return;
    }
    const int bn0 = blk * 16;
    {
        const int r = t >> 4, c = (t & 15) * 8;
        *(float4*)&wal[r][c]     = *(const float4*)&wa[r * FIN + c];
        *(float4*)&wal[r][c + 4] = *(const float4*)&wa[r * FIN + c + 4];
        *(float4*)&hrow[r][c]     = *(const float4*)&hsrc[(size_t)(bn0 + r) * FIN + c];
        *(float4*)&hrow[r][c + 4] = *(const float4*)&hsrc[(size_t)(bn0 + r) * FIN + c + 4];
    }
    __syncthreads();
    const int r = t >> 4, sub = t & 15;
    const int hd = sub >> 1, which = sub & 1;
    float s = 0.f;
#pragma unroll 8
    for (int k = 0; k < FIN; k += 4) {
        float4 hv = *(const float4*)&hrow[r][k];
        float4 wv = *(const float4*)&wal[sub][k];
        s += hv.x * wv.x + hv.y * wv.y + hv.z * wv.z + hv.w * wv.w;
    }
    const int bn = bn0 + r;
    if (which == 0) s1[(size_t)bn * 8 + hd] = s;
    else            s2T[(size_t)hd * (B_ * N_) + bn] = s;
}

// ---------------- K2: 2-heads-per-block fused P-gen + MFMA (P.h) + G@W epilogue ------
// (R17 structure + s_setprio around MFMA clusters — T5)
__global__ __launch_bounds__(256, 4) void k_pv2(const unsigned short* __restrict__ hbT,
                                                const float* __restrict__ s1,
                                                const float* __restrict__ s2T,
                                                const float* __restrict__ biasm,
                                                const unsigned short* __restrict__ WT,
                                                float* __restrict__ out) {
    __shared__ __align__(16) unsigned short P[2][32 * 64];   // 8 KB, XOR-swizzled
    __shared__ __align__(16) unsigned short Bl[128 * 64];    // 16 KB, XOR-swizzled
    __shared__ __align__(16) unsigned short Gl[32][136];     // 8.5 KB, padded
    __shared__ float Zl[2][32];
    const int t    = threadIdx.x;
    const int lane = t & 63;
    const int wave = t >> 6;
    const int wg  = blockIdx.x;
    const int swz = ((wg & 7) << 7) | (wg >> 3);   // bijective (1024 % 8 == 0)
    const int i0  = (swz & 31) * 32;
    const int hp  = (swz >> 5) & 3;
    const int b   = swz >> 7;
    const int hd0 = hp * 2, hd1 = hd0 + 1;

    const int prow = t >> 3;          // 0..31
    const int pj0  = (t & 7) * 8;     // 0..56
    const int pchk = (t & 7) ^ (prow & 7);   // swizzled P chunk for store
    const int gi   = (b << 10) + i0 + prow;
    const float s1v0 = s1[(size_t)gi * 8 + hd0];
    const float s1v1 = s1[(size_t)gi * 8 + hd1];
    const float* bm_row = biasm + (size_t)(i0 + prow) * N_;
    const float* s2p0   = s2T + (size_t)hd0 * (B_ * N_) + (b << 10);
    const float* s2p1   = s2T + (size_t)hd1 * (B_ * N_) + (b << 10);

    const unsigned short* hpS = hbT + (size_t)b * FIN * N_;
    const int brow = t >> 3;
    const int bc   = t & 7;

    const int wr = (wave & 1) * 16;
    const int wc = (wave >> 1) * 64;
    const int arow = wr + (lane & 15);
    const int koff = (lane >> 4) * 8;

    f32x4 acc0[4], acc1[4];
#pragma unroll
    for (int j = 0; j < 4; ++j) {
        acc0[j] = (f32x4){0.f, 0.f, 0.f, 0.f};
        acc1[j] = (f32x4){0.f, 0.f, 0.f, 0.f};
    }
    float z0 = 0.f, z1 = 0.f;

    float4 bmv[2], sv0[2], sv1[2];
    s16x8 Breg[4];

    auto load_it = [&](int j0) {
#pragma unroll
        for (int q = 0; q < 2; ++q) {
            bmv[q] = *(const float4*)&bm_row[j0 + pj0 + q * 4];
            sv0[q] = *(const float4*)&s2p0[j0 + pj0 + q * 4];
            sv1[q] = *(const float4*)&s2p1[j0 + pj0 + q * 4];
        }
    };
    auto bload = [&](int j0) {
#pragma unroll
        for (int q = 0; q < 4; ++q)
            Breg[q] = *(const s16x8*)&hpS[(size_t)(brow + q * 32) * N_ + j0 + bc * 8];
    };
    auto pgen = [&](int h, float s1v, const float4* svh, float& zr) {
        s16x8 pv;
#pragma unroll
        for (int q = 0; q < 2; ++q) {
            float x0 = s1v + svh[q].x; x0 = fmaxf(x0, NEG * x0) + bmv[q].x;
            float x1 = s1v + svh[q].y; x1 = fmaxf(x1, NEG * x1) + bmv[q].y;
            float x2 = s1v + svh[q].z; x2 = fmaxf(x2, NEG * x2) + bmv[q].z;
            float x3 = s1v + svh[q].w; x3 = fmaxf(x3, NEG * x3) + bmv[q].w;
            float p0 = exp2f(x0);   // exp2(-inf) = 0 handles the adj mask
            float p1 = exp2f(x1);
            float p2 = exp2f(x2);
            float p3 = exp2f(x3);
            zr += (p0 + p1) + (p2 + p3);
            pv[q * 4 + 0] = (short)f2bf_hw(p0);
            pv[q * 4 + 1] = (short)f2bf_hw(p1);
            pv[q * 4 + 2] = (short)f2bf_hw(p2);
            pv[q * 4 + 3] = (short)f2bf_hw(p3);
        }
        *(s16x8*)&P[h][prow * 64 + pchk * 8] = pv;
    };
    auto phaseA = [&]() {
#pragma unroll
        for (int q = 0; q < 4; ++q) {
            int row = brow + q * 32;
            *(s16x8*)&Bl[row * 64 + ((bc ^ (row & 7)) * 8)] = Breg[q];
        }
        pgen(0, s1v0, sv0, z0);
        pgen(1, s1v1, sv1, z1);
    };

    // ---- main loop: G_tile(h) = P(h) . h  — one staged B serves both heads
    bload(0);
    load_it(0);
    for (int it = 0; it < 16; ++it) {
        const int j0 = it * 64;
        phaseA();
        __syncthreads();
        if (it < 15) { bload(j0 + 64); load_it(j0 + 64); }
        __builtin_amdgcn_s_setprio(1);
#pragma unroll
        for (int kw = 0; kw < 2; ++kw) {
            const int chunk = kw * 4 + (lane >> 4);
            const int aoff = (chunk ^ (arow & 7)) * 8;
            s16x8 a00 = *(const s16x8*)&P[0][arow * 64 + aoff];
            s16x8 a01 = *(const s16x8*)&P[1][arow * 64 + aoff];
#pragma unroll
            for (int fc = 0; fc < 4; ++fc) {
                const int r = wc + fc * 16 + (lane & 15);
                s16x8 bf = *(const s16x8*)&Bl[r * 64 + ((chunk ^ (r & 7)) * 8)];
                acc0[fc] = __builtin_amdgcn_mfma_f32_16x16x32_bf16(a00, bf, acc0[fc], 0, 0, 0);
                acc1[fc] = __builtin_amdgcn_mfma_f32_16x16x32_bf16(a01, bf, acc1[fc], 0, 0, 0);
            }
        }
        __builtin_amdgcn_s_setprio(0);
        __syncthreads();
    }

    // ---- Z for both heads (8 lanes per row)
    {
        float za = z0, zb = z1;
        za += __shfl_xor(za, 1); za += __shfl_xor(za, 2); za += __shfl_xor(za, 4);
        zb += __shfl_xor(zb, 1); zb += __shfl_xor(zb, 2); zb += __shfl_xor(zb, 4);
        if ((t & 7) == 0) {
            Zl[0][prow] = 0.125f / za;   // folds softmax norm + head-mean
            Zl[1][prow] = 0.125f / zb;
        }
    }

    const unsigned short* Wsrc0 = WT + (size_t)hd0 * FOUT * FIN;
    const unsigned short* Wsrc1 = WT + (size_t)hd1 * FOUT * FIN;
    s16x8 Wreg[4];
#pragma unroll
    for (int q = 0; q < 4; ++q)
        Wreg[q] = *(const s16x8*)&Wsrc0[(size_t)(brow + q * 32) * FIN + bc * 8];
    __syncthreads();   // Zl visible; P/Bl free

    const int wr2 = (wave & 1) * 16;
    const int wc2 = (wave >> 1) * 64;
    f32x4 acc2[4];
#pragma unroll
    for (int j = 0; j < 4; ++j) acc2[j] = (f32x4){0.f, 0.f, 0.f, 0.f};

    auto wstage = [&]() {
#pragma unroll
        for (int q = 0; q < 4; ++q) {
            int row = brow + q * 32;
            *(s16x8*)&Bl[row * 64 + ((bc ^ (row & 7)) * 8)] = Wreg[q];
        }
    };
    auto gw_mfma = [&](int half) {
        __builtin_amdgcn_s_setprio(1);
#pragma unroll
        for (int kw = 0; kw < 2; ++kw) {
            const int chunk = kw * 4 + (lane >> 4);
            s16x8 a0 = *(const s16x8*)&Gl[wr2 + (lane & 15)][half * 64 + kw * 32 + koff];
#pragma unroll
            for (int fc = 0; fc < 4; ++fc) {
                const int rb = wc2 + fc * 16 + (lane & 15);
                s16x8 bf = *(const s16x8*)&Bl[rb * 64 + ((chunk ^ (rb & 7)) * 8)];
                acc2[fc] = __builtin_amdgcn_mfma_f32_16x16x32_bf16(a0, bf, acc2[fc], 0, 0, 0);
            }
        }
        __builtin_amdgcn_s_setprio(0);
    };

    // ---- head 0: out += G0 @ W[hd0]
#pragma unroll
    for (int r = 0; r < 4; ++r) {
        const int il = wr + (lane >> 4) * 4 + r;
        const float sc = Zl[0][il];
#pragma unroll
        for (int fc = 0; fc < 4; ++fc)
            Gl[il][wc + fc * 16 + (lane & 15)] = f2bf_hw(acc0[fc][r] * sc);
    }
    wstage();
#pragma unroll
    for (int q = 0; q < 4; ++q)
        Wreg[q] = *(const s16x8*)&Wsrc0[(size_t)(brow + q * 32) * FIN + 64 + bc * 8];
    __syncthreads();   // Gl(h0) + W0-half0 visible
    gw_mfma(0);
    __syncthreads();
    wstage();
#pragma unroll
    for (int q = 0; q < 4; ++q)
        Wreg[q] = *(const s16x8*)&Wsrc1[(size_t)(brow + q * 32) * FIN + bc * 8];
    __syncthreads();   // W0-half1 visible
    gw_mfma(1);
    __syncthreads();   // all waves done reading Gl(h0) + Bl

    // ---- head 1: out += G1 @ W[hd1]
#pragma unroll
    for (int r = 0; r < 4; ++r) {
        const int il = wr + (lane >> 4) * 4 + r;
        const float sc = Zl[1][il];
#pragma unroll
        for (int fc = 0; fc < 4; ++fc)
            Gl[il][wc + fc * 16 + (lane & 15)] = f2bf_hw(acc1[fc][r] * sc);
    }
    wstage();
#pragma unroll
    for (int q = 0; q < 4; ++q)
        Wreg[q] = *(const s16x8*)&Wsrc1[(size_t)(brow + q * 32) * FIN + 64 + bc * 8];
    __syncthreads();   // Gl(h1) + W1-half0 visible
    gw_mfma(0);
    __syncthreads();
    wstage();
    __syncthreads();   // W1-half1 visible
    gw_mfma(1);

    // ---- accumulate 2-head partial into out
#pragma unroll
    for (int r = 0; r < 4; ++r) {
        const int il = wr2 + (lane >> 4) * 4 + r;
        float* op = out + ((size_t)((b << 10) + i0 + il)) * FOUT + wc2 + (lane & 15);
#pragma unroll
        for (int fc = 0; fc < 4; ++fc)
            unsafeAtomicAdd(op + fc * 16, acc2[fc][r]);
    }
}

extern "C" void kernel_launch(void* const* d_in, const int* in_sizes, int n_in,
                              void* d_out, int out_size, void* d_ws, size_t ws_size,
                              hipStream_t stream) {
    const float* hsrc = (const float*)d_in[0];
    const int*   adj  = (const int*)d_in[1];
    const float* bias = (const float*)d_in[2];
    const float* W    = (const float*)d_in[3];
    const float* a    = (const float*)d_in[4];
    float* out = (float*)d_out;

    char* ws = (char*)d_ws;
    unsigned short* hbT = (unsigned short*)ws;                 // 2 MB (bf16 h^T per batch)
    float* s1    = (float*)(ws + 2097152);                     // 256 KB
    float* s2T   = s1 + 65536;                                 // 256 KB
    float* biasm = s2T + 65536;                                // 4 MB (f32, log2e-scaled)
    unsigned short* WT = (unsigned short*)(biasm + N_ * N_);   // 256 KB
    float* wa = (float*)(WT + (size_t)H_ * FOUT * FIN);        // 8 KB

    k_prep<<<dim3(1168), 256, 0, stream>>>(adj, bias, W, a, hsrc,
                                           biasm, WT, wa, hbT);
    k_s12<<<dim3(1024), 256, 0, stream>>>(hsrc, wa, s1, s2T, out);
    k_pv2<<<dim3(1024), 256, 0, stream>>>(hbT, s1, s2T, biasm, WT, out);
}

// Round 21
// 63.416 us; speedup vs baseline: 1.2604x; 1.0095x over previous
//
#include <hip/hip_runtime.h>
#include <hip/hip_bf16.h>
#include <math.h>

#define B_   8
#define N_   1024
#define FIN  128
#define FOUT 128
#define H_   8
#define NEG  0.2f
#define LOG2E 1.4426950408889634f

typedef __attribute__((ext_vector_type(4))) float f32x4;
typedef __attribute__((ext_vector_type(8))) short s16x8;

static __device__ __forceinline__ unsigned short f2bf(float f) {
    unsigned int u = __float_as_uint(f);
    unsigned int r = (u + 0x7fffu + ((u >> 16) & 1u)) >> 16;   // RNE (software)
    return (unsigned short)r;
}

static __device__ __forceinline__ unsigned short f2bf_hw(float f) {
    union { __hip_bfloat16 b; unsigned short u; } cv;
    cv.b = __float2bfloat16(f);
    return cv.u;
}

// ---------------- K_PREP: fused {bias-mask | W->WT | wa | h->hbT} --------------------
// grid 1168 (R17 layout — measured-good balance; wa precomputed ONCE, 8 blocks)
__global__ __launch_bounds__(256) void k_prep(const int* __restrict__ adj,
                                              const float* __restrict__ bias,
                                              const float* __restrict__ W,
                                              const float* __restrict__ a,
                                              const float* __restrict__ hsrc,
                                              float* __restrict__ biasm,
                                              unsigned short* __restrict__ WT,
                                              float* __restrict__ wa,
                                              unsigned short* __restrict__ hbT) {
    __shared__ float tf[64][132];
    const int blk = blockIdx.x;
    const int t   = threadIdx.x;

    if (blk < 1024) {
        // ---- biasm[i][j] = adj ? bias*log2e : -inf (f32), 4 elems/thread
        const int base = (blk * 256 + t) * 4;
        int4   av = *(const int4*)&adj[base];
        float4 bv = *(const float4*)&bias[base];
        const float NINF = -__builtin_inff();
        float4 r;
        r.x = av.x ? bv.x * LOG2E : NINF;
        r.y = av.y ? bv.y * LOG2E : NINF;
        r.z = av.z ? bv.z * LOG2E : NINF;
        r.w = av.w ? bv.w * LOG2E : NINF;
        *(float4*)&biasm[base] = r;
    } else if (blk < 1032) {
        // ---- WT[h][fout][fin] bf16
        const int hd  = blk - 1024;
        const int fo  = t >> 1;
        const int fi0 = (t & 1) * 64;
        const float* src = W + (size_t)hd * FIN * FOUT;
        unsigned short* dst = WT + ((size_t)hd * FOUT + fo) * FIN + fi0;
#pragma unroll
        for (int c = 0; c < 8; ++c) {
            s16x8 v;
#pragma unroll
            for (int u = 0; u < 8; ++u)
                v[u] = (short)f2bf(src[(size_t)(fi0 + c * 8 + u) * FOUT + fo]);
            *(s16x8*)(dst + c * 8) = v;
        }
    } else if (blk < 1040) {
        // ---- wa[h][which][k] = log2e * W[h][k][:] . a[h][which][:]
        const int hd = blk - 1032;
        const int which = t >> 7, k = t & 127;
        const float* wrow = W + ((size_t)hd * FIN + k) * FOUT;
        const float* av   = a + (size_t)hd * 2 * FOUT + which * FOUT;
        float s = 0.f;
#pragma unroll 8
        for (int f = 0; f < FOUT; f += 4) {
            float4 wv = *(const float4*)&wrow[f];
            float4 a4 = *(const float4*)&av[f];
            s += wv.x * a4.x + wv.y * a4.y + wv.z * a4.z + wv.w * a4.w;
        }
        wa[((size_t)hd * 2 + which) * FIN + k] = s * LOG2E;
    } else {
        // ---- hbT[b][k][n] bf16 transpose
        const int bn0 = (blk - 1040) * 64;
        const int b   = bn0 >> 10;
        const int n0  = bn0 & 1023;
        {
            const int r = t >> 2, k0 = (t & 3) * 32;
            const float* src = hsrc + (size_t)(bn0 + r) * FIN + k0;
#pragma unroll
            for (int c = 0; c < 8; ++c)
                *(float4*)&tf[r][k0 + c * 4] = *(const float4*)&src[c * 4];
        }
        __syncthreads();
        {
            const int k   = t >> 1;
            const int seg = (t & 1) * 32;
            unsigned short* dst = hbT + ((size_t)b * FIN + k) * N_ + n0 + seg;
#pragma unroll
            for (int c = 0; c < 4; ++c) {
                s16x8 v;
#pragma unroll
                for (int u = 0; u < 8; ++u)
                    v[u] = (short)f2bf_hw(tf[seg + c * 8 + u][k]);
                *(s16x8*)(dst + c * 8) = v;
            }
        }
    }
}

// ---------------- K0d: s1/s2 (blocks <512, reads precomputed wa) + zero-out ----------
__global__ __launch_bounds__(256) void k_s12(const float* __restrict__ hsrc,
                                             const float* __restrict__ wa,
                                             float* __restrict__ s1,
                                             float* __restrict__ s2T,
                                             float* __restrict__ outz) {
    __shared__ float hrow[16][132];
    __shared__ float wal[16][132];
    const int t   = threadIdx.x;
    const int blk = blockIdx.x;
    if (blk >= 512) {
        const int base = ((blk - 512) * 256 + t) * 8;
        const float4 z4 = make_float4(0.f, 0.f, 0.f, 0.f);
        *(float4*)&outz[base]     = z4;
        *(float4*)&outz[base + 4] = z4;
        return;
    }
    const int bn0 = blk * 16;
    {
        const int r = t >> 4, c = (t & 15) * 8;
        *(float4*)&wal[r][c]     = *(const float4*)&wa[r * FIN + c];
        *(float4*)&wal[r][c + 4] = *(const float4*)&wa[r * FIN + c + 4];
        *(float4*)&hrow[r][c]     = *(const float4*)&hsrc[(size_t)(bn0 + r) * FIN + c];
        *(float4*)&hrow[r][c + 4] = *(const float4*)&hsrc[(size_t)(bn0 + r) * FIN + c + 4];
    }
    __syncthreads();
    const int r = t >> 4, sub = t & 15;
    const int hd = sub >> 1, which = sub & 1;
    float s = 0.f;
#pragma unroll 8
    for (int k = 0; k < FIN; k += 4) {
        float4 hv = *(const float4*)&hrow[r][k];
        float4 wv = *(const float4*)&wal[sub][k];
        s += hv.x * wv.x + hv.y * wv.y + hv.z * wv.z + hv.w * wv.w;
    }
    const int bn = bn0 + r;
    if (which == 0) s1[(size_t)bn * 8 + hd] = s;
    else            s2T[(size_t)hd * (B_ * N_) + bn] = s;
}

// ---------------- K2: 2-heads-per-block fused P-gen + MFMA (P.h) + G@W epilogue ------
// (R17 verbatim — measured 48.8 us best)
__global__ __launch_bounds__(256, 4) void k_pv2(const unsigned short* __restrict__ hbT,
                                                const float* __restrict__ s1,
                                                const float* __restrict__ s2T,
                                                const float* __restrict__ biasm,
                                                const unsigned short* __restrict__ WT,
                                                float* __restrict__ out) {
    __shared__ __align__(16) unsigned short P[2][32 * 64];   // 8 KB, XOR-swizzled
    __shared__ __align__(16) unsigned short Bl[128 * 64];    // 16 KB, XOR-swizzled
    __shared__ __align__(16) unsigned short Gl[32][136];     // 8.5 KB, padded
    __shared__ float Zl[2][32];
    const int t    = threadIdx.x;
    const int lane = t & 63;
    const int wave = t >> 6;
    const int wg  = blockIdx.x;
    const int swz = ((wg & 7) << 7) | (wg >> 3);   // bijective (1024 % 8 == 0)
    const int i0  = (swz & 31) * 32;
    const int hp  = (swz >> 5) & 3;
    const int b   = swz >> 7;
    const int hd0 = hp * 2, hd1 = hd0 + 1;

    const int prow = t >> 3;          // 0..31
    const int pj0  = (t & 7) * 8;     // 0..56
    const int pchk = (t & 7) ^ (prow & 7);   // swizzled P chunk for store
    const int gi   = (b << 10) + i0 + prow;
    const float s1v0 = s1[(size_t)gi * 8 + hd0];
    const float s1v1 = s1[(size_t)gi * 8 + hd1];
    const float* bm_row = biasm + (size_t)(i0 + prow) * N_;
    const float* s2p0   = s2T + (size_t)hd0 * (B_ * N_) + (b << 10);
    const float* s2p1   = s2T + (size_t)hd1 * (B_ * N_) + (b << 10);

    const unsigned short* hpS = hbT + (size_t)b * FIN * N_;
    const int brow = t >> 3;
    const int bc   = t & 7;

    const int wr = (wave & 1) * 16;
    const int wc = (wave >> 1) * 64;
    const int arow = wr + (lane & 15);
    const int koff = (lane >> 4) * 8;

    f32x4 acc0[4], acc1[4];
#pragma unroll
    for (int j = 0; j < 4; ++j) {
        acc0[j] = (f32x4){0.f, 0.f, 0.f, 0.f};
        acc1[j] = (f32x4){0.f, 0.f, 0.f, 0.f};
    }
    float z0 = 0.f, z1 = 0.f;

    float4 bmv[2], sv0[2], sv1[2];
    s16x8 Breg[4];

    auto load_it = [&](int j0) {
#pragma unroll
        for (int q = 0; q < 2; ++q) {
            bmv[q] = *(const float4*)&bm_row[j0 + pj0 + q * 4];
            sv0[q] = *(const float4*)&s2p0[j0 + pj0 + q * 4];
            sv1[q] = *(const float4*)&s2p1[j0 + pj0 + q * 4];
        }
    };
    auto bload = [&](int j0) {
#pragma unroll
        for (int q = 0; q < 4; ++q)
            Breg[q] = *(const s16x8*)&hpS[(size_t)(brow + q * 32) * N_ + j0 + bc * 8];
    };
    auto pgen = [&](int h, float s1v, const float4* svh, float& zr) {
        s16x8 pv;
#pragma unroll
        for (int q = 0; q < 2; ++q) {
            float x0 = s1v + svh[q].x; x0 = fmaxf(x0, NEG * x0) + bmv[q].x;
            float x1 = s1v + svh[q].y; x1 = fmaxf(x1, NEG * x1) + bmv[q].y;
            float x2 = s1v + svh[q].z; x2 = fmaxf(x2, NEG * x2) + bmv[q].z;
            float x3 = s1v + svh[q].w; x3 = fmaxf(x3, NEG * x3) + bmv[q].w;
            float p0 = exp2f(x0);   // exp2(-inf) = 0 handles the adj mask
            float p1 = exp2f(x1);
            float p2 = exp2f(x2);
            float p3 = exp2f(x3);
            zr += (p0 + p1) + (p2 + p3);
            pv[q * 4 + 0] = (short)f2bf_hw(p0);
            pv[q * 4 + 1] = (short)f2bf_hw(p1);
            pv[q * 4 + 2] = (short)f2bf_hw(p2);
            pv[q * 4 + 3] = (short)f2bf_hw(p3);
        }
        *(s16x8*)&P[h][prow * 64 + pchk * 8] = pv;
    };
    auto phaseA = [&]() {
#pragma unroll
        for (int q = 0; q < 4; ++q) {
            int row = brow + q * 32;
            *(s16x8*)&Bl[row * 64 + ((bc ^ (row & 7)) * 8)] = Breg[q];
        }
        pgen(0, s1v0, sv0, z0);
        pgen(1, s1v1, sv1, z1);
    };

    // ---- main loop: G_tile(h) = P(h) . h  — one staged B serves both heads
    bload(0);
    load_it(0);
    for (int it = 0; it < 16; ++it) {
        const int j0 = it * 64;
        phaseA();
        __syncthreads();
        if (it < 15) { bload(j0 + 64); load_it(j0 + 64); }
#pragma unroll
        for (int kw = 0; kw < 2; ++kw) {
            const int chunk = kw * 4 + (lane >> 4);
            const int aoff = (chunk ^ (arow & 7)) * 8;
            s16x8 a00 = *(const s16x8*)&P[0][arow * 64 + aoff];
            s16x8 a01 = *(const s16x8*)&P[1][arow * 64 + aoff];
#pragma unroll
            for (int fc = 0; fc < 4; ++fc) {
                const int r = wc + fc * 16 + (lane & 15);
                s16x8 bf = *(const s16x8*)&Bl[r * 64 + ((chunk ^ (r & 7)) * 8)];
                acc0[fc] = __builtin_amdgcn_mfma_f32_16x16x32_bf16(a00, bf, acc0[fc], 0, 0, 0);
                acc1[fc] = __builtin_amdgcn_mfma_f32_16x16x32_bf16(a01, bf, acc1[fc], 0, 0, 0);
            }
        }
        __syncthreads();
    }

    // ---- Z for both heads (8 lanes per row)
    {
        float za = z0, zb = z1;
        za += __shfl_xor(za, 1); za += __shfl_xor(za, 2); za += __shfl_xor(za, 4);
        zb += __shfl_xor(zb, 1); zb += __shfl_xor(zb, 2); zb += __shfl_xor(zb, 4);
        if ((t & 7) == 0) {
            Zl[0][prow] = 0.125f / za;   // folds softmax norm + head-mean
            Zl[1][prow] = 0.125f / zb;
        }
    }

    const unsigned short* Wsrc0 = WT + (size_t)hd0 * FOUT * FIN;
    const unsigned short* Wsrc1 = WT + (size_t)hd1 * FOUT * FIN;
    s16x8 Wreg[4];
#pragma unroll
    for (int q = 0; q < 4; ++q)
        Wreg[q] = *(const s16x8*)&Wsrc0[(size_t)(brow + q * 32) * FIN + bc * 8];
    __syncthreads();   // Zl visible; P/Bl free

    const int wr2 = (wave & 1) * 16;
    const int wc2 = (wave >> 1) * 64;
    f32x4 acc2[4];
#pragma unroll
    for (int j = 0; j < 4; ++j) acc2[j] = (f32x4){0.f, 0.f, 0.f, 0.f};

    auto wstage = [&]() {
#pragma unroll
        for (int q = 0; q < 4; ++q) {
            int row = brow + q * 32;
            *(s16x8*)&Bl[row * 64 + ((bc ^ (row & 7)) * 8)] = Wreg[q];
        }
    };
    auto gw_mfma = [&](int half) {
#pragma unroll
        for (int kw = 0; kw < 2; ++kw) {
            const int chunk = kw * 4 + (lane >> 4);
            s16x8 a0 = *(const s16x8*)&Gl[wr2 + (lane & 15)][half * 64 + kw * 32 + koff];
#pragma unroll
            for (int fc = 0; fc < 4; ++fc) {
                const int rb = wc2 + fc * 16 + (lane & 15);
                s16x8 bf = *(const s16x8*)&Bl[rb * 64 + ((chunk ^ (rb & 7)) * 8)];
                acc2[fc] = __builtin_amdgcn_mfma_f32_16x16x32_bf16(a0, bf, acc2[fc], 0, 0, 0);
            }
        }
    };

    // ---- head 0: out += G0 @ W[hd0]
#pragma unroll
    for (int r = 0; r < 4; ++r) {
        const int il = wr + (lane >> 4) * 4 + r;
        const float sc = Zl[0][il];
#pragma unroll
        for (int fc = 0; fc < 4; ++fc)
            Gl[il][wc + fc * 16 + (lane & 15)] = f2bf_hw(acc0[fc][r] * sc);
    }
    wstage();
#pragma unroll
    for (int q = 0; q < 4; ++q)
        Wreg[q] = *(const s16x8*)&Wsrc0[(size_t)(brow + q * 32) * FIN + 64 + bc * 8];
    __syncthreads();   // Gl(h0) + W0-half0 visible
    gw_mfma(0);
    __syncthreads();
    wstage();
#pragma unroll
    for (int q = 0; q < 4; ++q)
        Wreg[q] = *(const s16x8*)&Wsrc1[(size_t)(brow + q * 32) * FIN + bc * 8];
    __syncthreads();   // W0-half1 visible
    gw_mfma(1);
    __syncthreads();   // all waves done reading Gl(h0) + Bl

    // ---- head 1: out += G1 @ W[hd1]
#pragma unroll
    for (int r = 0; r < 4; ++r) {
        const int il = wr + (lane >> 4) * 4 + r;
        const float sc = Zl[1][il];
#pragma unroll
        for (int fc = 0; fc < 4; ++fc)
            Gl[il][wc + fc * 16 + (lane & 15)] = f2bf_hw(acc1[fc][r] * sc);
    }
    wstage();
#pragma unroll
    for (int q = 0; q < 4; ++q)
        Wreg[q] = *(const s16x8*)&Wsrc1[(size_t)(brow + q * 32) * FIN + 64 + bc * 8];
    __syncthreads();   // Gl(h1) + W1-half0 visible
    gw_mfma(0);
    __syncthreads();
    wstage();
    __syncthreads();   // W1-half1 visible
    gw_mfma(1);

    // ---- accumulate 2-head partial into out
#pragma unroll
    for (int r = 0; r < 4; ++r) {
        const int il = wr2 + (lane >> 4) * 4 + r;
        float* op = out + ((size_t)((b << 10) + i0 + il)) * FOUT + wc2 + (lane & 15);
#pragma unroll
        for (int fc = 0; fc < 4; ++fc)
            unsafeAtomicAdd(op + fc * 16, acc2[fc][r]);
    }
}

extern "C" void kernel_launch(void* const* d_in, const int* in_sizes, int n_in,
                              void* d_out, int out_size, void* d_ws, size_t ws_size,
                              hipStream_t stream) {
    const float* hsrc = (const float*)d_in[0];
    const int*   adj  = (const int*)d_in[1];
    const float* bias = (const float*)d_in[2];
    const float* W    = (const float*)d_in[3];
    const float* a    = (const float*)d_in[4];
    float* out = (float*)d_out;

    char* ws = (char*)d_ws;
    unsigned short* hbT = (unsigned short*)ws;                 // 2 MB (bf16 h^T per batch)
    float* s1    = (float*)(ws + 2097152);                     // 256 KB
    float* s2T   = s1 + 65536;                                 // 256 KB
    float* biasm = s2T + 65536;                                // 4 MB (f32, log2e-scaled)
    unsigned short* WT = (unsigned short*)(biasm + N_ * N_);   // 256 KB
    float* wa = (float*)(WT + (size_t)H_ * FOUT * FIN);        // 8 KB

    k_prep<<<dim3(1168), 256, 0, stream>>>(adj, bias, W, a, hsrc,
                                           biasm, WT, wa, hbT);
    k_s12<<<dim3(1024), 256, 0, stream>>>(hsrc, wa, s1, s2T, out);
    k_pv2<<<dim3(1024), 256, 0, stream>>>(hbT, s1, s2T, biasm, WT, out);
}